// Round 3
// baseline (484.285 us; speedup 1.0000x reference)
//
#include <hip/hip_runtime.h>
#include <math.h>

#define NRAYS 16384
#define HID 64
#define GEO 15
#define NS 128
#define NUP 128
#define STOT 256

typedef float  float4_ __attribute__((ext_vector_type(4)));
typedef short  short8  __attribute__((ext_vector_type(8)));

#define LGKM0() __asm__ __volatile__("s_waitcnt lgkmcnt(0)" ::: "memory")

__device__ __forceinline__ float clip1(float v){ return fminf(fmaxf(v,-1.f),1.f); }
__device__ __forceinline__ float softplusf(float x){ return fmaxf(x,0.f)+log1pf(expf(-fabsf(x))); }
__device__ __forceinline__ float sigmoidf(float x){ return 1.f/(1.f+expf(-x)); }

__device__ __forceinline__ unsigned short f2bf(float f){
  unsigned int u = __float_as_uint(f);
  u = (u + 0x7fffu + ((u>>16)&1u)) >> 16;   // RNE
  return (unsigned short)u;
}

__device__ __forceinline__ void load_ray(const float* ro, const float* rd, int r,
    float& ox,float& oy,float& oz,float& dx,float& dy,float& dz){
  ox=ro[3*r]; oy=ro[3*r+1]; oz=ro[3*r+2];
  dx=rd[3*r]; dy=rd[3*r+1]; dz=rd[3*r+2];
  float inv = 1.f/sqrtf(dx*dx+dy*dy+dz*dz);
  dx*=inv; dy*=inv; dz*=inv;
}

__device__ __forceinline__ void aabb_nf(float ox,float oy,float oz,float dx,float dy,float dz,
    float& nears,float& fars){
  float dsx = (fabsf(dx)<1e-8f)?1e-8f:dx;
  float dsy = (fabsf(dy)<1e-8f)?1e-8f:dy;
  float dsz = (fabsf(dz)<1e-8f)?1e-8f:dz;
  float t1x=(-1.f-ox)/dsx, t2x=(1.f-ox)/dsx;
  float t1y=(-1.f-oy)/dsy, t2y=(1.f-oy)/dsy;
  float t1z=(-1.f-oz)/dsz, t2z=(1.f-oz)/dsz;
  float nr = fmaxf(fmaxf(fminf(t1x,t2x),fminf(t1y,t2y)),fminf(t1z,t2z));
  float fr = fminf(fminf(fmaxf(t1x,t2x),fmaxf(t1y,t2y)),fmaxf(t1z,t2z));
  fars  = fmaxf(fminf(fr,5.f),0.2f);
  nears = fminf(fmaxf(nr,0.2f),5.f);
}

// exclusive block scan (contains __syncthreads)
__device__ __forceinline__ float block_excl_scan(float v, float* lds_ws,
    int tid, int nwaves, float& total){
  float incl = v;
  #pragma unroll
  for(int off=1; off<64; off<<=1){
    float n = __shfl_up(incl, off, 64);
    if ((tid & 63) >= off) incl += n;
  }
  int wv = tid >> 6;
  if ((tid & 63) == 63) lds_ws[wv] = incl;
  __syncthreads();
  float woff = 0.f, tot = 0.f;
  for(int k=0;k<nwaves;k++){ float s = lds_ws[k]; tot += s; if (k < wv) woff += s; }
  __syncthreads();
  total = tot;
  return woff + incl - v;
}

// ---------------- weight prep: bf16 B-fragment order ----------------
// B-frag: lane l holds B[k = (l>>4)*8 + j][n = l&15] (K padded to 32)
// layout (ushort): [0,2048)   L1d: 4 N-tiles     (W1 3x64, K->32)
//                  [2048,3072) L2d: 2 K-steps    (W2 64x16)
//                  [3072,5120) L1c: 4 N-tiles    (Wc1 21x64, K->32)
//                  [5120,6144) L2c: 2 K-steps    (Wc2 64x3, N->16)
__global__ void prep_weights(const float* __restrict__ W1, const float* __restrict__ W2,
                             const float* __restrict__ Wc1, const float* __restrict__ Wc2,
                             unsigned short* __restrict__ wb){
  int idx = blockIdx.x*256 + threadIdx.x;
  if (idx >= 6144) return;
  int lane = (idx>>3)&63, j = idx&7, q = lane>>4, c = lane&15;
  float v;
  if (idx < 2048){ int t = idx>>9;        int k = q*8+j;       int n=t*16+c; v = (k<3) ? W1[k*HID+n] : 0.f; }
  else if (idx < 3072){ int ks=(idx-2048)>>9; int k = ks*32+q*8+j;            v = W2[k*16+c]; }
  else if (idx < 5120){ int t =(idx-3072)>>9; int k = q*8+j;   int n=t*16+c; v = (k<21)? Wc1[k*HID+n] : 0.f; }
  else            { int ks=(idx-5120)>>9; int k = ks*32+q*8+j;               v = (c<3) ? Wc2[k*3+c] : 0.f; }
  wb[idx] = f2bf(v);
}

#define HSTRIDE 72   // ushorts; 144B rows: 16B-aligned b128 reads, bank-spread
#define INPSTRIDE 40 // ushorts; 80B rows: 16B-aligned

// ---------------- kernel A: coarse+fine density (MFMA) + pdf ----------------
// 128 threads = 2 waves; wave w handles M-tiles w*4..w*4+3 (samples w*64..w*64+63)
__global__ __launch_bounds__(128) void density_kernel(
    const float* __restrict__ ro, const float* __restrict__ rd,
    const float* __restrict__ b1, const float* __restrict__ b2,
    const unsigned short* __restrict__ wb,
    float* __restrict__ sigma_c, float* __restrict__ newz, float* __restrict__ sigma_f)
{
  __shared__ unsigned short XA[128*8];        // 2 KB: per-sample bf16 [x,y,z,0,0,0,0,0]
  __shared__ unsigned short Hb[2*16*HSTRIDE]; // per-wave 16x64 H tile
  __shared__ float sig[128];
  __shared__ float cdf[128];
  __shared__ float sws[2];

  const int r = blockIdx.x;
  const int tid = threadIdx.x, lane = tid&63, wv = tid>>6;
  const int q = lane>>4, c = lane&15;

  float ox,oy,oz,dx,dy,dz;
  load_ray(ro,rd,r,ox,oy,oz,dx,dy,dz);
  float nears,fars; aabb_nf(ox,oy,oz,dx,dy,dz,nears,fars);
  const float step = (fars-nears)*(1.f/127.f);

  // B-frags + biases (wave-uniform reuse)
  const short8* WF = (const short8*)wb;
  short8 bL1[4], bL2[2];
  #pragma unroll
  for(int t=0;t<4;t++) bL1[t] = WF[t*64+lane];
  #pragma unroll
  for(int k=0;k<2;k++) bL2[k] = WF[256+k*64+lane];
  float biasL1[4];
  #pragma unroll
  for(int t=0;t<4;t++) biasL1[t] = b1[t*16+c];
  const float biasO = b2[c];

  for(int pass=0; pass<2; pass++){
    float z;
    if (pass==0){
      z = nears + step*(float)tid;
    } else {
      // ---- pdf from coarse sigmas (thread tid owns coarse sample tid) ----
      float sgv = sig[tid];
      float alpha = (tid<127) ? (1.f - expf(-step*sgv)) : 0.f;
      float l = (tid<127) ? logf(1.f - alpha + 1e-15f) : 0.f;
      float dummy;
      float S = block_excl_scan(l, sws, tid, 2, dummy);
      float w = alpha * expf(S);
      float ww = (tid>=1 && tid<127) ? (w + 1e-5f) : 0.f;
      float wsum;
      float ce = block_excl_scan(ww, sws, tid, 2, wsum);
      if (tid < 127) cdf[tid] = (ce + ww)/wsum;
      __syncthreads();
      const float u0 = 0.5f/128.f;
      const float du = (1.f - 1.f/128.f)/127.f;
      float u = u0 + du*(float)tid;
      int lo=0, hi=127;
      while(lo<hi){ int m=(lo+hi)>>1; if (cdf[m] <= u) lo=m+1; else hi=m; }
      int below = max(lo-1,0), above = min(lo,126);
      float c0 = cdf[below], c1 = cdf[above];
      float bb0 = nears + step*((float)below + 0.5f);
      float bb1 = nears + step*((float)above + 0.5f);
      float den = c1 - c0; if (den < 1e-5f) den = 1.f;
      z = bb0 + (u - c0)/den*(bb1 - bb0);
      newz[r*NUP + tid] = z;
      __syncthreads();   // sig[] reads done before overwrite
    }

    // stage bf16 position for sample tid
    unsigned short bx = f2bf(clip1(ox+dx*z));
    unsigned short by = f2bf(clip1(oy+dy*z));
    unsigned short bz = f2bf(clip1(oz+dz*z));
    unsigned int* xa = (unsigned int*)&XA[tid*8];
    xa[0] = (unsigned int)bx | ((unsigned int)by<<16);
    xa[1] = (unsigned int)bz;
    xa[2] = 0u; xa[3] = 0u;
    LGKM0();

    // density MLP for this wave's 4 M-tiles
    #pragma unroll
    for(int t=0;t<4;t++){
      int mt = wv*4 + t;
      short8 af = {0,0,0,0,0,0,0,0};
      if (q==0) af = *(const short8*)&XA[(mt*16+c)*8];
      float4_ acc[4];
      #pragma unroll
      for(int nt=0;nt<4;nt++){
        float bv = biasL1[nt];
        acc[nt] = (float4_){bv,bv,bv,bv};
        acc[nt] = __builtin_amdgcn_mfma_f32_16x16x32_bf16(af, bL1[nt], acc[nt], 0,0,0);
      }
      unsigned short* H = &Hb[wv*16*HSTRIDE];
      #pragma unroll
      for(int nt=0;nt<4;nt++)
        #pragma unroll
        for(int rr=0;rr<4;rr++)
          H[(q*4+rr)*HSTRIDE + nt*16 + c] = f2bf(fmaxf(acc[nt][rr], 0.f));
      LGKM0();
      short8 a0 = *(const short8*)&H[c*HSTRIDE + q*8];
      short8 a1 = *(const short8*)&H[c*HSTRIDE + 32 + q*8];
      float4_ o = (float4_){biasO,biasO,biasO,biasO};
      o = __builtin_amdgcn_mfma_f32_16x16x32_bf16(a0, bL2[0], o, 0,0,0);
      o = __builtin_amdgcn_mfma_f32_16x16x32_bf16(a1, bL2[1], o, 0,0,0);
      if (c==0){
        #pragma unroll
        for(int rr=0;rr<4;rr++) sig[mt*16 + q*4 + rr] = softplusf(o[rr]);
      }
      LGKM0();
    }
    __syncthreads();

    if (pass==0) sigma_c[r*NS + tid]  = sig[tid];
    else         sigma_f[r*NUP + tid] = sig[tid];
  }
}

// ---------------- kernel B: merge + composite + MFMA density(geo) + color ----------------
// 256 threads = 4 waves; wave w handles M-tiles w*4..w*4+3; thread s owns sample s
#define INPBYTES (256*INPSTRIDE*2)
#define HBYTES   (4*16*HSTRIDE*2)
#define RGBBYTES (256*4*4)

__global__ __launch_bounds__(256) void render_kernel(
    const float* __restrict__ ro, const float* __restrict__ rd,
    const float* __restrict__ b1, const float* __restrict__ b2,
    const float* __restrict__ bc1, const float* __restrict__ bc2,
    const unsigned short* __restrict__ wb,
    const float* __restrict__ sigma_c, const float* __restrict__ newz,
    const float* __restrict__ sigma_f, float* __restrict__ out)
{
  __shared__ __align__(16) char smem[INPBYTES + HBYTES + RGBBYTES + 96];
  unsigned short* Inp  = (unsigned short*)smem;
  unsigned short* Hbuf = (unsigned short*)(smem + INPBYTES);
  float* rgbb = (float*)(smem + INPBYTES + HBYTES);
  float* red  = (float*)(smem + INPBYTES + HBYTES + RGBBYTES);
  float* sws  = red + 16;
  // merge arrays alias the Hbuf region (used strictly before it)
  float* zA = (float*)(smem + INPBYTES);
  float* zB = zA + 128;
  float* zM = zB + 128;
  float* sM = zM + 257;

  const int r = blockIdx.x;
  const int s = threadIdx.x, lane = s&63, wv = s>>6;
  const int q = lane>>4, c = lane&15;

  float ox,oy,oz,dx,dy,dz;
  load_ray(ro,rd,r,ox,oy,oz,dx,dy,dz);
  float nears,fars; aabb_nf(ox,oy,oz,dx,dy,dz,nears,fars);
  const float step  = (fars-nears)*(1.f/127.f);
  const float sdist = (fars-nears)*(1.f/128.f);
  const bool asc = (nears <= fars);

  // B-frags + biases
  const short8* WF = (const short8*)wb;
  short8 bL1d[4], bL2d[2], bL1c[4], bL2c[2];
  #pragma unroll
  for(int t=0;t<4;t++){ bL1d[t] = WF[t*64+lane]; bL1c[t] = WF[384+t*64+lane]; }
  #pragma unroll
  for(int k=0;k<2;k++){ bL2d[k] = WF[256+k*64+lane]; bL2c[k] = WF[640+k*64+lane]; }
  float biasL1d[4], biasL1c[4];
  #pragma unroll
  for(int t=0;t<4;t++){ biasL1d[t] = b1[t*16+c]; biasL1c[t] = bc1[t*16+c]; }
  const float biasOd = b2[c];
  const float biasOc = (c<3) ? bc2[c] : 0.f;

  // ---- stage sorted lists ----
  float myz, mysig;
  if (s < 128){
    int i = asc ? s : (127 - s);
    myz = nears + step*(float)i;
    mysig = sigma_c[r*NS + i];
    zA[s] = myz;
  } else {
    int k = s - 128;
    int j = asc ? k : (127 - k);
    myz = newz[r*NUP + j];
    mysig = sigma_f[r*NUP + j];
    zB[k] = myz;
  }
  __syncthreads();

  // ---- merge path ----
  int pos;
  if (s < 128){
    int lo=0, hi=128;
    while(lo<hi){ int m=(lo+hi)>>1; if (zB[m] < myz) lo=m+1; else hi=m; }
    pos = s + lo;
  } else {
    int lo=0, hi=128;
    while(lo<hi){ int m=(lo+hi)>>1; if (zA[m] <= myz) lo=m+1; else hi=m; }
    pos = (s - 128) + lo;
  }
  zM[pos] = myz; sM[pos] = mysig;
  __syncthreads();

  // ---- composite (log-space scan) ----
  float zs = zM[s], sgs = sM[s];
  float delta = (s < STOT-1) ? (zM[s+1] - zs) : sdist;
  float alpha = 1.f - expf(-delta*sgs);
  float lg = logf(1.f - alpha + 1e-15f);
  float dummy;
  float S = block_excl_scan(lg, sws, s, 4, dummy);
  float w = alpha * expf(S);
  __syncthreads();   // all merge-region reads done before Hbuf reuse

  // ---- build Inp row for sample s: [x,y,z,dx,dy,dz,geo0..14,0...] ----
  float x = clip1(ox+dx*zs), y = clip1(oy+dy*zs), zz = clip1(oz+dz*zs);
  {
    unsigned int* row = (unsigned int*)&Inp[s*INPSTRIDE];
    row[0] = (unsigned int)f2bf(x)  | ((unsigned int)f2bf(y)<<16);
    row[1] = (unsigned int)f2bf(zz) | ((unsigned int)f2bf(dx)<<16);
    row[2] = (unsigned int)f2bf(dy) | ((unsigned int)f2bf(dz)<<16);
    row[3] = 0u;
    float4_ zr = (float4_){0.f,0.f,0.f,0.f};
    *(float4_*)&row[4]  = zr;
    *(float4_*)&row[8]  = zr;
    *(float4_*)&row[12] = zr;
    *(float4_*)&row[16] = zr;
  }
  LGKM0();

  // ---- density MLP (geo) for this wave's 4 M-tiles ----
  unsigned short* H = &Hbuf[wv*16*HSTRIDE];
  #pragma unroll
  for(int t=0;t<4;t++){
    int mt = wv*4 + t;
    short8 af = {0,0,0,0,0,0,0,0};
    if (q==0) af = *(const short8*)&Inp[(mt*16+c)*INPSTRIDE];
    float4_ acc[4];
    #pragma unroll
    for(int nt=0;nt<4;nt++){
      float bv = biasL1d[nt];
      acc[nt] = (float4_){bv,bv,bv,bv};
      acc[nt] = __builtin_amdgcn_mfma_f32_16x16x32_bf16(af, bL1d[nt], acc[nt], 0,0,0);
    }
    #pragma unroll
    for(int nt=0;nt<4;nt++)
      #pragma unroll
      for(int rr=0;rr<4;rr++)
        H[(q*4+rr)*HSTRIDE + nt*16 + c] = f2bf(fmaxf(acc[nt][rr], 0.f));
    LGKM0();
    short8 a0 = *(const short8*)&H[c*HSTRIDE + q*8];
    short8 a1 = *(const short8*)&H[c*HSTRIDE + 32 + q*8];
    float4_ o = (float4_){biasOd,biasOd,biasOd,biasOd};
    o = __builtin_amdgcn_mfma_f32_16x16x32_bf16(a0, bL2d[0], o, 0,0,0);
    o = __builtin_amdgcn_mfma_f32_16x16x32_bf16(a1, bL2d[1], o, 0,0,0);
    if (c >= 1){
      #pragma unroll
      for(int rr=0;rr<4;rr++)
        Inp[(mt*16 + q*4 + rr)*INPSTRIDE + 5 + c] = f2bf(o[rr]);
    }
    LGKM0();
  }

  // ---- color MLP for this wave's 4 M-tiles ----
  #pragma unroll
  for(int t=0;t<4;t++){
    int mt = wv*4 + t;
    short8 af = *(const short8*)&Inp[(mt*16+c)*INPSTRIDE + q*8];
    float4_ acc[4];
    #pragma unroll
    for(int nt=0;nt<4;nt++){
      float bv = biasL1c[nt];
      acc[nt] = (float4_){bv,bv,bv,bv};
      acc[nt] = __builtin_amdgcn_mfma_f32_16x16x32_bf16(af, bL1c[nt], acc[nt], 0,0,0);
    }
    #pragma unroll
    for(int nt=0;nt<4;nt++)
      #pragma unroll
      for(int rr=0;rr<4;rr++)
        H[(q*4+rr)*HSTRIDE + nt*16 + c] = f2bf(fmaxf(acc[nt][rr], 0.f));
    LGKM0();
    short8 a0 = *(const short8*)&H[c*HSTRIDE + q*8];
    short8 a1 = *(const short8*)&H[c*HSTRIDE + 32 + q*8];
    float4_ o = (float4_){biasOc,biasOc,biasOc,biasOc};
    o = __builtin_amdgcn_mfma_f32_16x16x32_bf16(a0, bL2c[0], o, 0,0,0);
    o = __builtin_amdgcn_mfma_f32_16x16x32_bf16(a1, bL2c[1], o, 0,0,0);
    if (c < 3){
      #pragma unroll
      for(int rr=0;rr<4;rr++)
        rgbb[(mt*16 + q*4 + rr)*4 + c] = sigmoidf(o[rr]);
    }
    LGKM0();
  }

  // ---- accumulate ----
  float cr=0.f, cg=0.f, cb=0.f;
  if (w > 1e-4f){
    cr = w*rgbb[s*4+0]; cg = w*rgbb[s*4+1]; cb = w*rgbb[s*4+2];
  }
  float wr = w;
  #pragma unroll
  for(int off=32; off; off>>=1){
    cr += __shfl_down(cr, off, 64);
    cg += __shfl_down(cg, off, 64);
    cb += __shfl_down(cb, off, 64);
    wr += __shfl_down(wr, off, 64);
  }
  if (lane == 0){ red[wv*4+0]=cr; red[wv*4+1]=cg; red[wv*4+2]=cb; red[wv*4+3]=wr; }
  __syncthreads();
  if (s == 0){
    float R=0.f,G=0.f,B=0.f,W=0.f;
    #pragma unroll
    for(int k=0;k<4;k++){ R+=red[k*4+0]; G+=red[k*4+1]; B+=red[k*4+2]; W+=red[k*4+3]; }
    float bg = 1.f - W;
    out[r*3+0] = R + bg;
    out[r*3+1] = G + bg;
    out[r*3+2] = B + bg;
  }
}

extern "C" void kernel_launch(void* const* d_in, const int* in_sizes, int n_in,
                              void* d_out, int out_size, void* d_ws, size_t ws_size,
                              hipStream_t stream) {
  const float* ro  = (const float*)d_in[0];
  const float* rd  = (const float*)d_in[1];
  const float* W1  = (const float*)d_in[2];
  const float* b1  = (const float*)d_in[3];
  const float* W2  = (const float*)d_in[4];
  const float* b2  = (const float*)d_in[5];
  const float* Wc1 = (const float*)d_in[6];
  const float* bc1 = (const float*)d_in[7];
  const float* Wc2 = (const float*)d_in[8];
  const float* bc2 = (const float*)d_in[9];
  float* out = (float*)d_out;

  float* ws = (float*)d_ws;
  float* sigma_c = ws;                          // NRAYS*128
  float* newz    = ws + (size_t)NRAYS*NS;       // NRAYS*128
  float* sigma_f = ws + (size_t)2*NRAYS*NS;     // NRAYS*128
  unsigned short* wb = (unsigned short*)(ws + (size_t)3*NRAYS*NS); // 6144 bf16

  prep_weights<<<dim3(24), dim3(256), 0, stream>>>(W1, W2, Wc1, Wc2, wb);
  density_kernel<<<dim3(NRAYS), dim3(128), 0, stream>>>(
      ro, rd, b1, b2, wb, sigma_c, newz, sigma_f);
  render_kernel<<<dim3(NRAYS), dim3(256), 0, stream>>>(
      ro, rd, b1, b2, bc1, bc2, wb, sigma_c, newz, sigma_f, out);
}

// Round 4
// 372.190 us; speedup vs baseline: 1.3012x; 1.3012x over previous
//
#include <hip/hip_runtime.h>
#include <math.h>

#define NRAYS 16384
#define HID 64
#define NS 128
#define NUP 128
#define STOT 256

typedef float  float4_ __attribute__((ext_vector_type(4)));
typedef short  short8  __attribute__((ext_vector_type(8)));

#define LGKM0() __asm__ __volatile__("s_waitcnt lgkmcnt(0)" ::: "memory")

#define HTS 20      // HT row stride in ushorts (40 B): b64-aligned writes, spread banks
#define ISTR 40     // Inp row stride in ushorts (80 B)

__device__ __forceinline__ float clip1(float v){ return fminf(fmaxf(v,-1.f),1.f); }
__device__ __forceinline__ float softplusf(float x){ return fmaxf(x,0.f)+log1pf(expf(-fabsf(x))); }
__device__ __forceinline__ float sigmoidf(float x){ return 1.f/(1.f+expf(-x)); }

__device__ __forceinline__ unsigned short f2bf(float f){          // RNE (prep only)
  unsigned int u = __float_as_uint(f);
  u = (u + 0x7fffu + ((u>>16)&1u)) >> 16;
  return (unsigned short)u;
}
// pack 2 floats -> 2 bf16 (round-half-up): a -> low16, b -> high16. 3 insts.
__device__ __forceinline__ unsigned int pk2bf(float a, float b){
  unsigned int au = __float_as_uint(a) + 0x8000u;
  unsigned int bu = __float_as_uint(b) + 0x8000u;
  return __builtin_amdgcn_perm(bu, au, 0x07060302u);
}
__device__ __forceinline__ unsigned short bf16ru(float v){
  return (unsigned short)((__float_as_uint(v) + 0x8000u) >> 16);
}

__device__ __forceinline__ void load_ray(const float* ro, const float* rd, int r,
    float& ox,float& oy,float& oz,float& dx,float& dy,float& dz){
  ox=ro[3*r]; oy=ro[3*r+1]; oz=ro[3*r+2];
  dx=rd[3*r]; dy=rd[3*r+1]; dz=rd[3*r+2];
  float inv = 1.f/sqrtf(dx*dx+dy*dy+dz*dz);
  dx*=inv; dy*=inv; dz*=inv;
}

__device__ __forceinline__ void aabb_nf(float ox,float oy,float oz,float dx,float dy,float dz,
    float& nears,float& fars){
  float dsx = (fabsf(dx)<1e-8f)?1e-8f:dx;
  float dsy = (fabsf(dy)<1e-8f)?1e-8f:dy;
  float dsz = (fabsf(dz)<1e-8f)?1e-8f:dz;
  float t1x=(-1.f-ox)/dsx, t2x=(1.f-ox)/dsx;
  float t1y=(-1.f-oy)/dsy, t2y=(1.f-oy)/dsy;
  float t1z=(-1.f-oz)/dsz, t2z=(1.f-oz)/dsz;
  float nr = fmaxf(fmaxf(fminf(t1x,t2x),fminf(t1y,t2y)),fminf(t1z,t2z));
  float fr = fminf(fminf(fmaxf(t1x,t2x),fmaxf(t1y,t2y)),fmaxf(t1z,t2z));
  fars  = fmaxf(fminf(fr,5.f),0.2f);
  nears = fminf(fmaxf(nr,0.2f),5.f);
}

// exclusive block scan (contains __syncthreads)
__device__ __forceinline__ float block_excl_scan(float v, float* lds_ws,
    int tid, int nwaves, float& total){
  float incl = v;
  #pragma unroll
  for(int off=1; off<64; off<<=1){
    float n = __shfl_up(incl, off, 64);
    if ((tid & 63) >= off) incl += n;
  }
  int wv = tid >> 6;
  if ((tid & 63) == 63) lds_ws[wv] = incl;
  __syncthreads();
  float woff = 0.f, tot = 0.f;
  for(int k=0;k<nwaves;k++){ float s = lds_ws[k]; tot += s; if (k < wv) woff += s; }
  __syncthreads();
  total = tot;
  return woff + incl - v;
}

// ---------------- weight prep ----------------
// frag-slot f = slot*64 + lane, 8 ushorts each. q=lane>>4, c=lane&15.
// slots 0..3 : W1  B-frags (N-tile t):  B[k=q*8+j][n=t*16+c], k>=3 -> 0
// slots 4..5 : W2^T A-frags (K-step ks): A[m=c][k=ks*32+q*8+j] = W2[k][c]
// slots 6..9 : Wc1 B-frags (N-tile t):  k>=21 -> 0
// slots 10..11: Wc2^T A-frags:          A[m=c][k] = (c<3)? Wc2[k][c] : 0
__global__ void prep_weights(const float* __restrict__ W1, const float* __restrict__ W2,
                             const float* __restrict__ Wc1, const float* __restrict__ Wc2,
                             unsigned short* __restrict__ wb){
  int idx = blockIdx.x*256 + threadIdx.x;
  if (idx >= 6144) return;
  int f = idx>>3, j = idx&7, lane = f&63, slot = f>>6, q = lane>>4, c = lane&15;
  float v;
  if (slot < 4){       int k=q*8+j;              v = (k<3)  ? W1[k*HID + slot*16 + c]     : 0.f; }
  else if (slot < 6){  int k=(slot-4)*32+q*8+j;  v = W2[k*16 + c]; }
  else if (slot < 10){ int k=q*8+j;              v = (k<21) ? Wc1[k*HID + (slot-6)*16+c] : 0.f; }
  else {               int k=(slot-10)*32+q*8+j; v = (c<3)  ? Wc2[k*3 + c]               : 0.f; }
  wb[idx] = f2bf(v);
}

// store relu'd layer-1 C-tile (acc[nt]) into HT[hdim][sample] (transposed), b64 packed
__device__ __forceinline__ void store_HT(unsigned short* ht, const float4_* acc,
                                         int q, int c){
  #pragma unroll
  for(int nt=0;nt<4;nt++){
    unsigned int d0 = pk2bf(fmaxf(acc[nt][0],0.f), fmaxf(acc[nt][1],0.f));
    unsigned int d1 = pk2bf(fmaxf(acc[nt][2],0.f), fmaxf(acc[nt][3],0.f));
    unsigned long long dd = (unsigned long long)d0 | ((unsigned long long)d1<<32);
    *(unsigned long long*)&ht[(nt*16+c)*HTS + q*4] = dd;
  }
}
// read layer-2 B-frag (K-step ks) from HT
__device__ __forceinline__ short8 read_BT(const unsigned short* ht, int ks, int q, int c){
  short8 b;
  #pragma unroll
  for(int j=0;j<8;j++)
    ((unsigned short*)&b)[j] = ht[(ks*32 + q*8 + j)*HTS + c];
  return b;
}

// ---------------- kernel A: coarse density + pdf + fine density ----------------
// 128 threads = 2 waves; wave wv owns tiles wv*4..wv*4+3 (samples wv*64..wv*64+63)
__global__ __launch_bounds__(128) void density_kernel(
    const float* __restrict__ ro, const float* __restrict__ rd,
    const float* __restrict__ b1, const float* __restrict__ b2,
    const unsigned short* __restrict__ wb,
    float* __restrict__ sigma_c, float* __restrict__ newz, float* __restrict__ sigma_f)
{
  __shared__ __align__(16) unsigned short XA[128*8];      // 2 KB
  __shared__ __align__(16) unsigned short HT[2][2][64*HTS]; // 2 waves x dbuf x 2.5KB
  __shared__ float sig[128];
  __shared__ float cdf[128];
  __shared__ float sws[2];

  const int r = blockIdx.x;
  const int tid = threadIdx.x, lane = tid&63, wv = tid>>6;
  const int q = lane>>4, c = lane&15;

  float ox,oy,oz,dx,dy,dz;
  load_ray(ro,rd,r,ox,oy,oz,dx,dy,dz);
  float nears,fars; aabb_nf(ox,oy,oz,dx,dy,dz,nears,fars);
  const float step = (fars-nears)*(1.f/127.f);

  const short8* WF = (const short8*)wb;
  short8 bW1[4], aW2T[2];
  #pragma unroll
  for(int t=0;t<4;t++) bW1[t] = WF[t*64+lane];
  #pragma unroll
  for(int k=0;k<2;k++) aW2T[k] = WF[256+k*64+lane];
  float biasL1[4];
  #pragma unroll
  for(int t=0;t<4;t++) biasL1[t] = b1[t*16+c];
  float bT[4];
  #pragma unroll
  for(int rr=0;rr<4;rr++) bT[rr] = b2[q*4+rr];

  for(int pass=0; pass<2; pass++){
    float z;
    if (pass==0){
      z = nears + step*(float)tid;
    } else {
      LGKM0();
      float sgv = sig[tid];
      float alpha = (tid<127) ? (1.f - expf(-step*sgv)) : 0.f;
      float l = (tid<127) ? logf(1.f - alpha + 1e-15f) : 0.f;
      float dummy;
      float S = block_excl_scan(l, sws, tid, 2, dummy);
      float w = alpha * expf(S);
      float ww = (tid>=1 && tid<127) ? (w + 1e-5f) : 0.f;
      float wsum;
      float ce = block_excl_scan(ww, sws, tid, 2, wsum);
      if (tid < 127) cdf[tid] = (ce + ww)/wsum;
      __syncthreads();
      const float u0 = 0.5f/128.f;
      const float du = (1.f - 1.f/128.f)/127.f;
      float u = u0 + du*(float)tid;
      int lo=0, hi=127;
      while(lo<hi){ int m=(lo+hi)>>1; if (cdf[m] <= u) lo=m+1; else hi=m; }
      int below = max(lo-1,0), above = min(lo,126);
      float c0 = cdf[below], c1 = cdf[above];
      float bb0 = nears + step*((float)below + 0.5f);
      float bb1 = nears + step*((float)above + 0.5f);
      float den = c1 - c0; if (den < 1e-5f) den = 1.f;
      z = bb0 + (u - c0)/den*(bb1 - bb0);
      newz[r*NUP + tid] = z;
      __syncthreads();
    }

    // stage bf16 position (row = 8 ushorts = 16B, zero-padded)
    {
      unsigned int d0 = pk2bf(clip1(ox+dx*z), clip1(oy+dy*z));
      unsigned int d1 = pk2bf(clip1(oz+dz*z), 0.f);
      float4_ rowv;
      ((unsigned int*)&rowv)[0] = d0; ((unsigned int*)&rowv)[1] = d1;
      ((unsigned int*)&rowv)[2] = 0u; ((unsigned int*)&rowv)[3] = 0u;
      *(float4_*)&XA[tid*8] = rowv;
    }
    LGKM0();

    #pragma unroll
    for(int t=0;t<4;t++){
      int mt = wv*4 + t;
      short8 af = (short8){0,0,0,0,0,0,0,0};
      if (q==0) af = *(const short8*)&XA[(mt*16+c)*8];
      float4_ acc[4];
      #pragma unroll
      for(int nt=0;nt<4;nt++){
        float bv = biasL1[nt];
        acc[nt] = (float4_){bv,bv,bv,bv};
        acc[nt] = __builtin_amdgcn_mfma_f32_16x16x32_bf16(af, bW1[nt], acc[nt], 0,0,0);
      }
      unsigned short* ht = HT[wv][t&1];
      store_HT(ht, acc, q, c);
      LGKM0();
      float4_ o = (float4_){bT[0],bT[1],bT[2],bT[3]};
      o = __builtin_amdgcn_mfma_f32_16x16x32_bf16(aW2T[0], read_BT(ht,0,q,c), o, 0,0,0);
      o = __builtin_amdgcn_mfma_f32_16x16x32_bf16(aW2T[1], read_BT(ht,1,q,c), o, 0,0,0);
      if (q==0) sig[mt*16+c] = softplusf(o[0]);   // outdim 0 = sigma, sample = c
    }
    LGKM0();
    if (pass==0) sigma_c[r*NS + tid]  = sig[tid];
    else         sigma_f[r*NUP + tid] = sig[tid];
  }
}

// ---------------- kernel B: merge + composite + geo + color + accumulate ----------------
// 256 threads = 4 waves; wave wv owns tiles wv*4..wv*4+3; thread s owns sample s
__global__ __launch_bounds__(256) void render_kernel(
    const float* __restrict__ ro, const float* __restrict__ rd,
    const float* __restrict__ b1, const float* __restrict__ b2,
    const float* __restrict__ bc1, const float* __restrict__ bc2,
    const unsigned short* __restrict__ wb,
    const float* __restrict__ sigma_c, const float* __restrict__ newz,
    const float* __restrict__ sigma_f, float* __restrict__ out)
{
  __shared__ __align__(16) unsigned short Inp[256*ISTR];        // 20 KB
  __shared__ __align__(16) unsigned short HTs[4][2][64*HTS];    // 20 KB (merge aliases)
  __shared__ float rgbb[256*4];                                 // 4 KB
  __shared__ float red[16];
  __shared__ float swsR[4];
  float* zA = (float*)HTs;        // [128]
  float* zB = zA + 128;           // [128]
  float* zM = zB + 128;           // [257]
  float* sM = zM + 257;           // [256]

  const int r = blockIdx.x;
  const int s = threadIdx.x, lane = s&63, wv = s>>6;
  const int q = lane>>4, c = lane&15;

  float ox,oy,oz,dx,dy,dz;
  load_ray(ro,rd,r,ox,oy,oz,dx,dy,dz);
  float nears,fars; aabb_nf(ox,oy,oz,dx,dy,dz,nears,fars);
  const float step  = (fars-nears)*(1.f/127.f);
  const float sdist = (fars-nears)*(1.f/128.f);
  const bool asc = (nears <= fars);

  const short8* WF = (const short8*)wb;
  short8 bW1[4], aW2T[2], bWc1[4], aWc2T[2];
  #pragma unroll
  for(int t=0;t<4;t++){ bW1[t] = WF[t*64+lane]; bWc1[t] = WF[384+t*64+lane]; }
  #pragma unroll
  for(int k=0;k<2;k++){ aW2T[k] = WF[256+k*64+lane]; aWc2T[k] = WF[640+k*64+lane]; }
  float biasL1d[4], biasL1c[4], bTd[4], bTc[4];
  #pragma unroll
  for(int t=0;t<4;t++){ biasL1d[t] = b1[t*16+c]; biasL1c[t] = bc1[t*16+c]; }
  #pragma unroll
  for(int rr=0;rr<4;rr++){
    bTd[rr] = b2[q*4+rr];
    bTc[rr] = (q*4+rr < 3) ? bc2[q*4+rr] : 0.f;
  }

  // ---- stage sorted lists ----
  float myz, mysig;
  if (s < 128){
    int i = asc ? s : (127 - s);
    myz = nears + step*(float)i;
    mysig = sigma_c[r*NS + i];
    zA[s] = myz;
  } else {
    int k = s - 128;
    int j = asc ? k : (127 - k);
    myz = newz[r*NUP + j];
    mysig = sigma_f[r*NUP + j];
    zB[k] = myz;
  }
  __syncthreads();

  // ---- merge path ----
  int pos;
  if (s < 128){
    int lo=0, hi=128;
    while(lo<hi){ int m=(lo+hi)>>1; if (zB[m] < myz) lo=m+1; else hi=m; }
    pos = s + lo;
  } else {
    int lo=0, hi=128;
    while(lo<hi){ int m=(lo+hi)>>1; if (zA[m] <= myz) lo=m+1; else hi=m; }
    pos = (s - 128) + lo;
  }
  zM[pos] = myz; sM[pos] = mysig;
  __syncthreads();

  // ---- composite (log-space scan) ----
  float zs = zM[s], sgs = sM[s];
  float delta = (s < STOT-1) ? (zM[s+1] - zs) : sdist;
  float alpha = 1.f - expf(-delta*sgs);
  float lg = logf(1.f - alpha + 1e-15f);
  float dummy;
  float S = block_excl_scan(lg, swsR, s, 4, dummy);
  float w = alpha * expf(S);
  __syncthreads();   // merge region (aliases HTs) free after this

  // ---- build Inp row: cols 0..5 = x,y,z,dx,dy,dz ; cols 6..31 zeroed ----
  float x = clip1(ox+dx*zs), y = clip1(oy+dy*zs), zz = clip1(oz+dz*zs);
  {
    unsigned short* row = &Inp[s*ISTR];
    *(unsigned int*)&row[0] = pk2bf(x, y);
    *(unsigned int*)&row[2] = pk2bf(zz, dx);
    *(unsigned int*)&row[4] = pk2bf(dy, dz);
    *(unsigned int*)&row[6] = 0u;
    float4_ zr = (float4_){0.f,0.f,0.f,0.f};
    *(float4_*)&row[8]  = zr;
    *(float4_*)&row[16] = zr;
    *(float4_*)&row[24] = zr;
  }
  LGKM0();

  // ---- density MLP -> geo (cols 6..20 of Inp) ----
  #pragma unroll
  for(int t=0;t<4;t++){
    int mt = wv*4 + t;
    short8 af = *(const short8*)&Inp[(mt*16+c)*ISTR + q*8];  // k>=3 killed by zero B rows
    float4_ acc[4];
    #pragma unroll
    for(int nt=0;nt<4;nt++){
      float bv = biasL1d[nt];
      acc[nt] = (float4_){bv,bv,bv,bv};
      acc[nt] = __builtin_amdgcn_mfma_f32_16x16x32_bf16(af, bW1[nt], acc[nt], 0,0,0);
    }
    unsigned short* ht = HTs[wv][t&1];
    store_HT(ht, acc, q, c);
    LGKM0();
    float4_ o = (float4_){bTd[0],bTd[1],bTd[2],bTd[3]};
    o = __builtin_amdgcn_mfma_f32_16x16x32_bf16(aW2T[0], read_BT(ht,0,q,c), o, 0,0,0);
    o = __builtin_amdgcn_mfma_f32_16x16x32_bf16(aW2T[1], read_BT(ht,1,q,c), o, 0,0,0);
    // lane holds outdims q*4+rr for sample c; geo d=1..15 -> Inp col 5+d
    #pragma unroll
    for(int rr=0;rr<4;rr++){
      int d = q*4+rr;
      if (d >= 1) Inp[(mt*16+c)*ISTR + 5 + d] = bf16ru(o[rr]);
    }
  }
  LGKM0();

  // ---- color MLP ----
  #pragma unroll
  for(int t=0;t<4;t++){
    int mt = wv*4 + t;
    short8 af = *(const short8*)&Inp[(mt*16+c)*ISTR + q*8];  // k 0..31; >=21 killed by B
    float4_ acc[4];
    #pragma unroll
    for(int nt=0;nt<4;nt++){
      float bv = biasL1c[nt];
      acc[nt] = (float4_){bv,bv,bv,bv};
      acc[nt] = __builtin_amdgcn_mfma_f32_16x16x32_bf16(af, bWc1[nt], acc[nt], 0,0,0);
    }
    unsigned short* ht = HTs[wv][t&1];
    store_HT(ht, acc, q, c);
    LGKM0();
    float4_ o = (float4_){bTc[0],bTc[1],bTc[2],bTc[3]};
    o = __builtin_amdgcn_mfma_f32_16x16x32_bf16(aWc2T[0], read_BT(ht,0,q,c), o, 0,0,0);
    o = __builtin_amdgcn_mfma_f32_16x16x32_bf16(aWc2T[1], read_BT(ht,1,q,c), o, 0,0,0);
    if (q==0){
      #pragma unroll
      for(int rr=0;rr<3;rr++)
        rgbb[(mt*16+c)*4 + rr] = sigmoidf(o[rr]);
    }
  }
  LGKM0();

  // ---- accumulate ----
  float cr=0.f, cg=0.f, cb=0.f;
  if (w > 1e-4f){
    float4_ rv = *(float4_*)&rgbb[s*4];
    cr = w*rv[0]; cg = w*rv[1]; cb = w*rv[2];
  }
  float wr = w;
  #pragma unroll
  for(int off=32; off; off>>=1){
    cr += __shfl_down(cr, off, 64);
    cg += __shfl_down(cg, off, 64);
    cb += __shfl_down(cb, off, 64);
    wr += __shfl_down(wr, off, 64);
  }
  if (lane == 0){ red[wv*4+0]=cr; red[wv*4+1]=cg; red[wv*4+2]=cb; red[wv*4+3]=wr; }
  __syncthreads();
  if (s == 0){
    float R=0.f,G=0.f,B=0.f,W=0.f;
    #pragma unroll
    for(int k=0;k<4;k++){ R+=red[k*4+0]; G+=red[k*4+1]; B+=red[k*4+2]; W+=red[k*4+3]; }
    float bg = 1.f - W;
    out[r*3+0] = R + bg;
    out[r*3+1] = G + bg;
    out[r*3+2] = B + bg;
  }
}

extern "C" void kernel_launch(void* const* d_in, const int* in_sizes, int n_in,
                              void* d_out, int out_size, void* d_ws, size_t ws_size,
                              hipStream_t stream) {
  const float* ro  = (const float*)d_in[0];
  const float* rd  = (const float*)d_in[1];
  const float* W1  = (const float*)d_in[2];
  const float* b1  = (const float*)d_in[3];
  const float* W2  = (const float*)d_in[4];
  const float* b2  = (const float*)d_in[5];
  const float* Wc1 = (const float*)d_in[6];
  const float* bc1 = (const float*)d_in[7];
  const float* Wc2 = (const float*)d_in[8];
  const float* bc2 = (const float*)d_in[9];
  float* out = (float*)d_out;

  float* ws = (float*)d_ws;
  float* sigma_c = ws;                          // NRAYS*128
  float* newz    = ws + (size_t)NRAYS*NS;       // NRAYS*128
  float* sigma_f = ws + (size_t)2*NRAYS*NS;     // NRAYS*128
  unsigned short* wb = (unsigned short*)(ws + (size_t)3*NRAYS*NS); // 6144 bf16

  prep_weights<<<dim3(24), dim3(256), 0, stream>>>(W1, W2, Wc1, Wc2, wb);
  density_kernel<<<dim3(NRAYS), dim3(128), 0, stream>>>(
      ro, rd, b1, b2, wb, sigma_c, newz, sigma_f);
  render_kernel<<<dim3(NRAYS), dim3(256), 0, stream>>>(
      ro, rd, b1, b2, bc1, bc2, wb, sigma_c, newz, sigma_f, out);
}

// Round 5
// 333.961 us; speedup vs baseline: 1.4501x; 1.1145x over previous
//
#include <hip/hip_runtime.h>
#include <math.h>

#define NRAYS 16384
#define HID 64
#define NS 128
#define NUP 128
#define STOT 256

typedef float  float4_ __attribute__((ext_vector_type(4)));
typedef short  short8  __attribute__((ext_vector_type(8)));

#define LGKM0() __asm__ __volatile__("s_waitcnt lgkmcnt(0)" ::: "memory")

#define HSTR 72     // H row stride (ushorts); 144B: 16B-aligned b128, 2-way banks max
#define ISTR 40     // Inp row stride (ushorts); 80B: 16B-aligned b128, 2-way banks max

__device__ __forceinline__ float clip1(float v){ return fminf(fmaxf(v,-1.f),1.f); }
__device__ __forceinline__ float softplusf(float x){ return fmaxf(x,0.f)+log1pf(expf(-fabsf(x))); }
__device__ __forceinline__ float sigmoidf(float x){ return 1.f/(1.f+expf(-x)); }

__device__ __forceinline__ unsigned short f2bf(float f){          // RNE (prep only)
  unsigned int u = __float_as_uint(f);
  u = (u + 0x7fffu + ((u>>16)&1u)) >> 16;
  return (unsigned short)u;
}
// pack 2 floats -> 2 bf16 (round-half-up): a -> low16, b -> high16
__device__ __forceinline__ unsigned int pk2bf(float a, float b){
  unsigned int au = __float_as_uint(a) + 0x8000u;
  unsigned int bu = __float_as_uint(b) + 0x8000u;
  return __builtin_amdgcn_perm(bu, au, 0x07060302u);
}

__device__ __forceinline__ void load_ray(const float* ro, const float* rd, int r,
    float& ox,float& oy,float& oz,float& dx,float& dy,float& dz){
  ox=ro[3*r]; oy=ro[3*r+1]; oz=ro[3*r+2];
  dx=rd[3*r]; dy=rd[3*r+1]; dz=rd[3*r+2];
  float inv = 1.f/sqrtf(dx*dx+dy*dy+dz*dz);
  dx*=inv; dy*=inv; dz*=inv;
}

__device__ __forceinline__ void aabb_nf(float ox,float oy,float oz,float dx,float dy,float dz,
    float& nears,float& fars){
  float dsx = (fabsf(dx)<1e-8f)?1e-8f:dx;
  float dsy = (fabsf(dy)<1e-8f)?1e-8f:dy;
  float dsz = (fabsf(dz)<1e-8f)?1e-8f:dz;
  float t1x=(-1.f-ox)/dsx, t2x=(1.f-ox)/dsx;
  float t1y=(-1.f-oy)/dsy, t2y=(1.f-oy)/dsy;
  float t1z=(-1.f-oz)/dsz, t2z=(1.f-oz)/dsz;
  float nr = fmaxf(fmaxf(fminf(t1x,t2x),fminf(t1y,t2y)),fminf(t1z,t2z));
  float fr = fminf(fminf(fmaxf(t1x,t2x),fmaxf(t1y,t2y)),fmaxf(t1z,t2z));
  fars  = fmaxf(fminf(fr,5.f),0.2f);
  nears = fminf(fmaxf(nr,0.2f),5.f);
}

// exclusive block scan (contains __syncthreads)
__device__ __forceinline__ float block_excl_scan(float v, float* lds_ws,
    int tid, int nwaves, float& total){
  float incl = v;
  #pragma unroll
  for(int off=1; off<64; off<<=1){
    float n = __shfl_up(incl, off, 64);
    if ((tid & 63) >= off) incl += n;
  }
  int wv = tid >> 6;
  if ((tid & 63) == 63) lds_ws[wv] = incl;
  __syncthreads();
  float woff = 0.f, tot = 0.f;
  for(int k=0;k<nwaves;k++){ float s = lds_ws[k]; tot += s; if (k < wv) woff += s; }
  __syncthreads();
  total = tot;
  return woff + incl - v;
}

// ---------------- weight prep: A-fragments (transposed weights) ----------------
// A-frag: lane l holds A[m=l&15][k=(l>>4)*8+j], j=0..7. 12 slots of 64 lanes x 8 ushorts:
// slots 0..3 : W1^T  (M-tile mt: m=h=mt*16+c):  A = W1[k][h], k>=3 -> 0
// slots 4..5 : W2^T  (K-step ks: k=h=ks*32+..): A = W2[h][od=c]
// slots 6..9 : Wc1^T (M-tile mt), PERMUTED k:   k=0 -> 0 row; k in 1..15 -> geo_{k-1}
//              (Wc1 row 5+k); k in 16..21 -> pos/dir (Wc1 row k-16); k>=22 -> 0
// slots 10..11: Wc2^T: A = (c<3)? Wc2[h][c] : 0
__global__ void prep_weights(const float* __restrict__ W1, const float* __restrict__ W2,
                             const float* __restrict__ Wc1, const float* __restrict__ Wc2,
                             unsigned short* __restrict__ wb){
  int idx = blockIdx.x*256 + threadIdx.x;
  if (idx >= 6144) return;
  int f = idx>>3, j = idx&7, lane = f&63, slot = f>>6, q = lane>>4, c = lane&15;
  int k = q*8+j;
  float v = 0.f;
  if (slot < 4){        if (k<3) v = W1[k*HID + slot*16 + c]; }
  else if (slot < 6){   int h=(slot-4)*32+k; v = W2[h*16 + c]; }
  else if (slot < 10){  int mt=slot-6;
                        int row = (k==0)? -1 : (k<16 ? 5+k : (k<22 ? k-16 : -1));
                        if (row>=0) v = Wc1[row*HID + mt*16 + c]; }
  else {                int h=(slot-10)*32+k; if (c<3) v = Wc2[h*3 + c]; }
  wb[idx] = f2bf(v);
}

// relu+pack a layer-1 C tile (h rows) and b64-store into H[sample][h]
__device__ __forceinline__ void store_H(unsigned short* H, const float4_ acc,
                                        int mt, int q, int c){
  unsigned int p0 = pk2bf(fmaxf(acc[0],0.f), fmaxf(acc[1],0.f));
  unsigned int p1 = pk2bf(fmaxf(acc[2],0.f), fmaxf(acc[3],0.f));
  *(unsigned long long*)&H[c*HSTR + mt*16 + q*4] =
      (unsigned long long)p0 | ((unsigned long long)p1<<32);
}

// ---------------- kernel A: coarse density + pdf + fine density ----------------
// 128 threads = 2 waves; wave wv owns samples wv*64..wv*64+63 (4 groups of 16)
__global__ __launch_bounds__(128) void density_kernel(
    const float* __restrict__ ro, const float* __restrict__ rd,
    const float* __restrict__ b1, const float* __restrict__ b2,
    const unsigned short* __restrict__ wb,
    float* __restrict__ sigma_c, float* __restrict__ newz, float* __restrict__ sigma_f)
{
  __shared__ __align__(16) unsigned short Hd[2][16*HSTR];
  __shared__ float sig[128];
  __shared__ float cdf[128];
  __shared__ float newzL[128];
  __shared__ float sws[2];

  const int r = blockIdx.x;
  const int tid = threadIdx.x, lane = tid&63, wv = tid>>6;
  const int q = lane>>4, c = lane&15;

  float ox,oy,oz,dx,dy,dz;
  load_ray(ro,rd,r,ox,oy,oz,dx,dy,dz);
  float nears,fars; aabb_nf(ox,oy,oz,dx,dy,dz,nears,fars);
  const float step = (fars-nears)*(1.f/127.f);

  const short8* WF = (const short8*)wb;
  short8 aW1T[4], aW2T[2];
  #pragma unroll
  for(int t=0;t<4;t++) aW1T[t] = WF[t*64+lane];
  #pragma unroll
  for(int k=0;k<2;k++) aW2T[k] = WF[(4+k)*64+lane];
  float4_ b1v[4];
  #pragma unroll
  for(int t=0;t<4;t++) b1v[t] = *(const float4_*)&b1[t*16+q*4];
  const float4_ bTd = *(const float4_*)&b2[q*4];

  unsigned short* Hw = Hd[wv];

  for(int pass=0; pass<2; pass++){
    if (pass==1){
      // ---- pdf from coarse sigmas (thread tid owns coarse sample tid) ----
      float sgv = sig[tid];
      float alpha = (tid<127) ? (1.f - expf(-step*sgv)) : 0.f;
      float l = (tid<127) ? logf(1.f - alpha + 1e-15f) : 0.f;
      float dummy;
      float S = block_excl_scan(l, sws, tid, 2, dummy);
      float w = alpha * expf(S);
      float ww = (tid>=1 && tid<127) ? (w + 1e-5f) : 0.f;
      float wsum;
      float ce = block_excl_scan(ww, sws, tid, 2, wsum);
      if (tid < 127) cdf[tid] = (ce + ww)/wsum;
      __syncthreads();
      const float u0 = 0.5f/128.f;
      const float du = (1.f - 1.f/128.f)/127.f;
      float u = u0 + du*(float)tid;
      int lo=0, hi=127;
      while(lo<hi){ int m=(lo+hi)>>1; if (cdf[m] <= u) lo=m+1; else hi=m; }
      int below = max(lo-1,0), above = min(lo,126);
      float c0 = cdf[below], c1 = cdf[above];
      float bb0 = nears + step*((float)below + 0.5f);
      float bb1 = nears + step*((float)above + 0.5f);
      float den = c1 - c0; if (den < 1e-5f) den = 1.f;
      float zfine = bb0 + (u - c0)/den*(bb1 - bb0);
      newzL[tid] = zfine;
      newz[r*NUP + tid] = zfine;
      __syncthreads();
    }

    #pragma unroll
    for(int g=0; g<4; g++){
      int sidx = wv*64 + g*16 + c;
      short8 bf = {0,0,0,0,0,0,0,0};
      if (q==0){
        float z = pass ? newzL[sidx] : (nears + step*(float)sidx);
        unsigned int* bu = (unsigned int*)&bf;
        bu[0] = pk2bf(clip1(ox+dx*z), clip1(oy+dy*z));
        bu[1] = pk2bf(clip1(oz+dz*z), 0.f);
      }
      float4_ acc;
      #pragma unroll
      for(int t=0;t<4;t++){
        acc = b1v[t];
        acc = __builtin_amdgcn_mfma_f32_16x16x32_bf16(aW1T[t], bf, acc, 0,0,0);
        store_H(Hw, acc, t, q, c);
      }
      LGKM0();
      short8 h0 = *(const short8*)&Hw[c*HSTR + q*8];
      short8 h1 = *(const short8*)&Hw[c*HSTR + 32 + q*8];
      float4_ o = bTd;
      o = __builtin_amdgcn_mfma_f32_16x16x32_bf16(aW2T[0], h0, o, 0,0,0);
      o = __builtin_amdgcn_mfma_f32_16x16x32_bf16(aW2T[1], h1, o, 0,0,0);
      if (q==0) sig[sidx] = softplusf(o[0]);   // outdim0, sample c
      LGKM0();   // H reads done before next group's writes
    }
    if (pass==0) sigma_c[r*NS + tid]  = sig[tid];
    else         sigma_f[r*NUP + tid] = sig[tid];
  }
}

// ---------------- kernel B: merge + composite + geo + color + accumulate ----------------
// 256 threads = 4 waves; wave wv owns samples wv*64..+63 (4 groups of 16); thread s owns sample s
__global__ __launch_bounds__(256) void render_kernel(
    const float* __restrict__ ro, const float* __restrict__ rd,
    const float* __restrict__ b1, const float* __restrict__ b2,
    const float* __restrict__ bc1, const float* __restrict__ bc2,
    const unsigned short* __restrict__ wb,
    const float* __restrict__ sigma_c, const float* __restrict__ newz,
    const float* __restrict__ sigma_f, float* __restrict__ out)
{
  __shared__ __align__(16) unsigned short Inp[256*ISTR];   // 20 KB: [k0..15]=od, [16..21]=pos/dir
  __shared__ __align__(16) unsigned short Hb[4][16*HSTR];  // 9 KB (merge aliases)
  __shared__ float wLDS[256];
  __shared__ float red[16];
  __shared__ float swsR[4];
  float* zA = (float*)Hb;         // [128]
  float* zB = zA + 128;           // [128]
  float* zM = zB + 128;           // [257]
  float* sM = zM + 257;           // [256]

  const int r = blockIdx.x;
  const int s = threadIdx.x, lane = s&63, wv = s>>6;
  const int q = lane>>4, c = lane&15;

  float ox,oy,oz,dx,dy,dz;
  load_ray(ro,rd,r,ox,oy,oz,dx,dy,dz);
  float nears,fars; aabb_nf(ox,oy,oz,dx,dy,dz,nears,fars);
  const float step  = (fars-nears)*(1.f/127.f);
  const float sdist = (fars-nears)*(1.f/128.f);
  const bool asc = (nears <= fars);

  const short8* WF = (const short8*)wb;
  short8 aW1T[4], aW2T[2], aWc1T[4], aWc2T[2];
  #pragma unroll
  for(int t=0;t<4;t++){ aW1T[t] = WF[t*64+lane]; aWc1T[t] = WF[(6+t)*64+lane]; }
  #pragma unroll
  for(int k=0;k<2;k++){ aW2T[k] = WF[(4+k)*64+lane]; aWc2T[k] = WF[(10+k)*64+lane]; }
  float4_ b1v[4], bc1v[4];
  #pragma unroll
  for(int t=0;t<4;t++){
    b1v[t]  = *(const float4_*)&b1[t*16+q*4];
    bc1v[t] = *(const float4_*)&bc1[t*16+q*4];
  }
  const float4_ bTd = *(const float4_*)&b2[q*4];
  float4_ bTc = (float4_){0.f,0.f,0.f,0.f};
  if (q==0){ bTc[0]=bc2[0]; bTc[1]=bc2[1]; bTc[2]=bc2[2]; }

  // ---- stage sorted lists ----
  float myz, mysig;
  if (s < 128){
    int i = asc ? s : (127 - s);
    myz = nears + step*(float)i;
    mysig = sigma_c[r*NS + i];
    zA[s] = myz;
  } else {
    int k = s - 128;
    int j = asc ? k : (127 - k);
    myz = newz[r*NUP + j];
    mysig = sigma_f[r*NUP + j];
    zB[k] = myz;
  }
  __syncthreads();

  // ---- merge path ----
  int pos;
  if (s < 128){
    int lo=0, hi=128;
    while(lo<hi){ int m=(lo+hi)>>1; if (zB[m] < myz) lo=m+1; else hi=m; }
    pos = s + lo;
  } else {
    int lo=0, hi=128;
    while(lo<hi){ int m=(lo+hi)>>1; if (zA[m] <= myz) lo=m+1; else hi=m; }
    pos = (s - 128) + lo;
  }
  zM[pos] = myz; sM[pos] = mysig;
  __syncthreads();

  // ---- composite (log-space scan) ----
  float zs = zM[s], sgs = sM[s];
  float delta = (s < STOT-1) ? (zM[s+1] - zs) : sdist;
  float alpha = 1.f - expf(-delta*sgs);
  float lg = logf(1.f - alpha + 1e-15f);
  float dummy;
  float S = block_excl_scan(lg, swsR, s, 4, dummy);   // trailing sync frees merge region
  float w = alpha * expf(S);
  wLDS[s] = w;

  // ---- Inp row: pos/dir at k16..21, zeros k22..31 (geo k0..15 written per group) ----
  float x = clip1(ox+dx*zs), y = clip1(oy+dy*zs), zz = clip1(oz+dz*zs);
  {
    unsigned short* row = &Inp[s*ISTR];
    *(unsigned int*)&row[16] = pk2bf(x, y);
    *(unsigned int*)&row[18] = pk2bf(zz, dx);
    *(unsigned int*)&row[20] = pk2bf(dy, dz);
    *(unsigned int*)&row[22] = 0u;
    *(float4_*)&row[24] = (float4_){0.f,0.f,0.f,0.f};
  }
  LGKM0();

  float accR=0.f, accG=0.f, accB=0.f, accW=0.f;
  unsigned short* Hw = Hb[wv];

  #pragma unroll
  for(int g=0; g<4; g++){
    const int srow = wv*64 + g*16 + c;    // this lane's sample for group g
    // ---- density MLP -> geo (ods) ----
    short8 bf = {0,0,0,0,0,0,0,0};
    if (q==0) bf = *(const short8*)&Inp[srow*ISTR + 16];  // [x,y,z,dx,dy,dz,0,0]; k>=3 dead in A
    float4_ acc;
    #pragma unroll
    for(int t=0;t<4;t++){
      acc = b1v[t];
      acc = __builtin_amdgcn_mfma_f32_16x16x32_bf16(aW1T[t], bf, acc, 0,0,0);
      store_H(Hw, acc, t, q, c);
    }
    LGKM0();
    short8 h0 = *(const short8*)&Hw[c*HSTR + q*8];
    short8 h1 = *(const short8*)&Hw[c*HSTR + 32 + q*8];
    float4_ o = bTd;
    o = __builtin_amdgcn_mfma_f32_16x16x32_bf16(aW2T[0], h0, o, 0,0,0);
    o = __builtin_amdgcn_mfma_f32_16x16x32_bf16(aW2T[1], h1, o, 0,0,0);
    // geo: lane holds ods q*4..q*4+3 of sample srow -> Inp[srow][q*4..] (od0 has zero Wc1 row)
    {
      unsigned int p0 = pk2bf(o[0], o[1]);
      unsigned int p1 = pk2bf(o[2], o[3]);
      *(unsigned long long*)&Inp[srow*ISTR + q*4] =
          (unsigned long long)p0 | ((unsigned long long)p1<<32);
    }
    LGKM0();

    // ---- color MLP ----
    short8 bcf = *(const short8*)&Inp[srow*ISTR + q*8];   // permuted input dims
    #pragma unroll
    for(int t=0;t<4;t++){
      acc = bc1v[t];
      acc = __builtin_amdgcn_mfma_f32_16x16x32_bf16(aWc1T[t], bcf, acc, 0,0,0);
      store_H(Hw, acc, t, q, c);
    }
    LGKM0();
    h0 = *(const short8*)&Hw[c*HSTR + q*8];
    h1 = *(const short8*)&Hw[c*HSTR + 32 + q*8];
    float4_ oc = bTc;
    oc = __builtin_amdgcn_mfma_f32_16x16x32_bf16(aWc2T[0], h0, oc, 0,0,0);
    oc = __builtin_amdgcn_mfma_f32_16x16x32_bf16(aWc2T[1], h1, oc, 0,0,0);
    if (q==0){
      float wgt = wLDS[srow];
      if (wgt > 1e-4f){
        accR += wgt*sigmoidf(oc[0]);
        accG += wgt*sigmoidf(oc[1]);
        accB += wgt*sigmoidf(oc[2]);
      }
      accW += wgt;
    }
    LGKM0();   // H/Inp-geo reads done before next group's writes
  }

  // ---- reduce (only q==0 lanes carry nonzero) ----
  #pragma unroll
  for(int off=32; off; off>>=1){
    accR += __shfl_down(accR, off, 64);
    accG += __shfl_down(accG, off, 64);
    accB += __shfl_down(accB, off, 64);
    accW += __shfl_down(accW, off, 64);
  }
  if (lane == 0){ red[wv*4+0]=accR; red[wv*4+1]=accG; red[wv*4+2]=accB; red[wv*4+3]=accW; }
  __syncthreads();
  if (s == 0){
    float R=0.f,G=0.f,B=0.f,W=0.f;
    #pragma unroll
    for(int k=0;k<4;k++){ R+=red[k*4+0]; G+=red[k*4+1]; B+=red[k*4+2]; W+=red[k*4+3]; }
    float bg = 1.f - W;
    out[r*3+0] = R + bg;
    out[r*3+1] = G + bg;
    out[r*3+2] = B + bg;
  }
}

extern "C" void kernel_launch(void* const* d_in, const int* in_sizes, int n_in,
                              void* d_out, int out_size, void* d_ws, size_t ws_size,
                              hipStream_t stream) {
  const float* ro  = (const float*)d_in[0];
  const float* rd  = (const float*)d_in[1];
  const float* W1  = (const float*)d_in[2];
  const float* b1  = (const float*)d_in[3];
  const float* W2  = (const float*)d_in[4];
  const float* b2  = (const float*)d_in[5];
  const float* Wc1 = (const float*)d_in[6];
  const float* bc1 = (const float*)d_in[7];
  const float* Wc2 = (const float*)d_in[8];
  const float* bc2 = (const float*)d_in[9];
  float* out = (float*)d_out;

  float* ws = (float*)d_ws;
  float* sigma_c = ws;                          // NRAYS*128
  float* newz    = ws + (size_t)NRAYS*NS;       // NRAYS*128
  float* sigma_f = ws + (size_t)2*NRAYS*NS;     // NRAYS*128
  unsigned short* wb = (unsigned short*)(ws + (size_t)3*NRAYS*NS); // 6144 bf16

  prep_weights<<<dim3(24), dim3(256), 0, stream>>>(W1, W2, Wc1, Wc2, wb);
  density_kernel<<<dim3(NRAYS), dim3(128), 0, stream>>>(
      ro, rd, b1, b2, wb, sigma_c, newz, sigma_f);
  render_kernel<<<dim3(NRAYS), dim3(256), 0, stream>>>(
      ro, rd, b1, b2, bc1, bc2, wb, sigma_c, newz, sigma_f, out);
}